// Round 13
// baseline (206.271 us; speedup 1.0000x reference)
//
#include <hip/hip_runtime.h>
#include <hip/hip_fp16.h>

#define Bn  4
#define Hn  256
#define Wn  256
#define Cn  16
#define NTn 9
#define HWn (Hn*Wn)
#define KF  129      // W/2 + 1
#define KGP 136      // padded k-row length of G
#define SRL 266      // scratch row length (bank-stagger padded)
#define PI_F 3.14159265358979323846f

__device__ __forceinline__ int swz(int i) { return i ^ ((i >> 4) & 15); }

__device__ __forceinline__ void lds_fence() {
  __asm__ volatile("s_waitcnt lgkmcnt(0)" ::: "memory");
}

__device__ __forceinline__ float2 cmul(float2 a, float2 b) {
  return make_float2(a.x*b.x - a.y*b.y, a.x*b.y + a.y*b.x);
}

template<bool INV>
__device__ __forceinline__ void radix4(float2& x0, float2& x1, float2& x2, float2& x3) {
  float2 y0 = make_float2(x0.x + x2.x, x0.y + x2.y);
  float2 y1 = make_float2(x0.x - x2.x, x0.y - x2.y);
  float2 y2 = make_float2(x1.x + x3.x, x1.y + x3.y);
  float2 y3 = make_float2(x1.x - x3.x, x1.y - x3.y);
  x0 = make_float2(y0.x + y2.x, y0.y + y2.y);
  x2 = make_float2(y0.x - y2.x, y0.y - y2.y);
  if (!INV) {
    x1 = make_float2(y1.x + y3.y, y1.y - y3.x);   // y1 - i*y3
    x3 = make_float2(y1.x - y3.y, y1.y + y3.x);   // y1 + i*y3
  } else {
    x1 = make_float2(y1.x - y3.y, y1.y + y3.x);
    x3 = make_float2(y1.x + y3.y, y1.y - y3.x);
  }
}

struct Tw { float2 a1,a2,a3,b1,b2,b3,c1,c2,c3; };

template<bool INV>
__device__ __forceinline__ Tw make_tw(int lane) {
  const float sgn = INV ? 2.0f * PI_F : -2.0f * PI_F;
  Tw t; float sw, cw;
  __sincosf(sgn * (float)lane / 256.0f, &sw, &cw);
  t.a1 = make_float2(cw, sw); t.a2 = cmul(t.a1, t.a1); t.a3 = cmul(t.a2, t.a1);
  __sincosf(sgn * (float)(lane & 15) / 64.0f, &sw, &cw);
  t.b1 = make_float2(cw, sw); t.b2 = cmul(t.b1, t.b1); t.b3 = cmul(t.b2, t.b1);
  __sincosf(sgn * (float)(lane & 3) / 16.0f, &sw, &cw);
  t.c1 = make_float2(cw, sw); t.c2 = cmul(t.c1, t.c1); t.c3 = cmul(t.c2, t.c1);
  return t;
}

// ---------------------------------------------------------------------------
// NF per-wave FFT-256s in lockstep (fence amortized NF-fold).
// Input v[f][a] = x_f[lane+64a]; output natural order in s[f][swz(k)].
// ---------------------------------------------------------------------------
template<bool INV, int NF>
__device__ __forceinline__ void fft256_n(float2 (*v)[4], float2 (*s)[SRL],
                                         int lane, const Tw& t) {
#pragma unroll
  for (int f = 0; f < NF; ++f) {
    radix4<INV>(v[f][0], v[f][1], v[f][2], v[f][3]);
    v[f][1] = cmul(v[f][1], t.a1); v[f][2] = cmul(v[f][2], t.a2); v[f][3] = cmul(v[f][3], t.a3);
#pragma unroll
    for (int a = 0; a < 4; ++a) s[f][swz(lane + (a << 6))] = v[f][a];
  }
  lds_fence();
  { int base = (lane >> 4) * 64 + (lane & 15);
#pragma unroll
    for (int f = 0; f < NF; ++f)
#pragma unroll
      for (int a = 0; a < 4; ++a) v[f][a] = s[f][swz(base + (a << 4))];
  }
  lds_fence();
#pragma unroll
  for (int f = 0; f < NF; ++f) {
    radix4<INV>(v[f][0], v[f][1], v[f][2], v[f][3]);
    v[f][1] = cmul(v[f][1], t.b1); v[f][2] = cmul(v[f][2], t.b2); v[f][3] = cmul(v[f][3], t.b3);
    int base = (lane >> 4) * 64 + (lane & 15);
#pragma unroll
    for (int a = 0; a < 4; ++a) s[f][swz(base + (a << 4))] = v[f][a];
  }
  lds_fence();
  { int base = (lane >> 4) * 64 + ((lane >> 2) & 3) * 16 + (lane & 3);
#pragma unroll
    for (int f = 0; f < NF; ++f)
#pragma unroll
      for (int a = 0; a < 4; ++a) v[f][a] = s[f][swz(base + (a << 2))];
  }
  lds_fence();
#pragma unroll
  for (int f = 0; f < NF; ++f) {
    radix4<INV>(v[f][0], v[f][1], v[f][2], v[f][3]);
    v[f][1] = cmul(v[f][1], t.c1); v[f][2] = cmul(v[f][2], t.c2); v[f][3] = cmul(v[f][3], t.c3);
    int base = (lane & ~3) * 4 + (lane & 3);
#pragma unroll
    for (int a = 0; a < 4; ++a) s[f][swz(base + (a << 2))] = v[f][a];
  }
  lds_fence();
  { int base = lane * 4;
#pragma unroll
    for (int f = 0; f < NF; ++f)
#pragma unroll
      for (int a = 0; a < 4; ++a) v[f][a] = s[f][swz(base + a)];
  }
  lds_fence();
  int dr = ((lane & 3) << 4) + (((lane >> 2) & 3) << 2) + (lane >> 4);
#pragma unroll
  for (int f = 0; f < NF; ++f) {
    radix4<INV>(v[f][0], v[f][1], v[f][2], v[f][3]);
#pragma unroll
    for (int a = 0; a < 4; ++a) s[f][swz(dr + (a << 6))] = v[f][a];
  }
  lds_fence();
}

// Inline projective warp map (matches reference: fp-contract off, rintf).
__device__ __forceinline__ int warp_id(float a0, float a1, float a2, float a3,
                                       float a4, float a5, float a6, float a7,
                                       int col, int row) {
#pragma clang fp contract(off)
  float x = (float)col, y = (float)row;
  float kk = a6 * x + a7 * y + 1.0f;
  float xf = (a0 * x + a1 * y + a2) / kk;
  float yf = (a3 * x + a4 * y + a5) / kk;
  float xr = rintf(xf), yr = rintf(yf);
  bool valid = (xr >= 0.f) && (xr < 256.f) && (yr >= 0.f) && (yr < 256.f);
  return valid ? ((int)yr * Wn + (int)xr) : -1;
}

// ---------------------------------------------------------------------------
// Pure gather: 1 thread = 1 warped pixel. Reads the pixel's full 64B channel
// line, converts to fp16, writes one contiguous 32B granule of Wh[tb][p][c].
// No LDS, low VGPR -> high occupancy, massive MLP.
// ---------------------------------------------------------------------------
__global__ __launch_bounds__(256) void k_gather(const float* __restrict__ inp,
                                                const float* __restrict__ T,
                                                __half* __restrict__ Wh) {
  int tb = blockIdx.x >> 8;                  // t*Bn + b
  int p = ((blockIdx.x & 255) << 8) + threadIdx.x;
  int b = tb & 3, tt = tb >> 2;
  int i = p >> 8, j = p & 255;
  const float* a = T + tt * 8;
  int id = warp_id(a[0],a[1],a[2],a[3],a[4],a[5],a[6],a[7], j, i);
  const float4* ib = (const float4*)(inp + (size_t)b * HWn * Cn);
  float4 x0, x1, x2, x3;
  if (id >= 0) {
    const float4* pp = ib + (size_t)id * 4;
    x0 = pp[0]; x1 = pp[1]; x2 = pp[2]; x3 = pp[3];
  } else {
    x0 = x1 = x2 = x3 = make_float4(0.f, 0.f, 0.f, 0.f);
  }
  union { __half2 h[8]; float4 f[2]; } u;
  u.h[0] = __floats2half2_rn(x0.x, x0.y); u.h[1] = __floats2half2_rn(x0.z, x0.w);
  u.h[2] = __floats2half2_rn(x1.x, x1.y); u.h[3] = __floats2half2_rn(x1.z, x1.w);
  u.h[4] = __floats2half2_rn(x2.x, x2.y); u.h[5] = __floats2half2_rn(x2.z, x2.w);
  u.h[6] = __floats2half2_rn(x3.x, x3.y); u.h[7] = __floats2half2_rn(x3.z, x3.w);
  float4* dst = (float4*)(Wh + ((size_t)tb * HWn + p) * Cn);
  dst[0] = u.f[0];
  dst[1] = u.f[1];
}

// ---------------------------------------------------------------------------
// Row FFT of warped image (t=0 slab == x spectra). Block = (tb, cq channel-
// quad, 16-row chunk). Wave w reads its row-pair from Wh (contiguous-ish),
// q4-batched real-pair FFTs, Hermitian-unpack store phase from scratch
// (cross-wave, 32B granules). Race-free norm partials.
// ---------------------------------------------------------------------------
__global__ __launch_bounds__(256) void k_yfft(const __half* __restrict__ Wh,
                                              __half2* __restrict__ Yh,
                                              float* __restrict__ part) {
  __shared__ float2 sb[4][4][SRL];
  __shared__ float4 redw[4];
  int tid = threadIdx.x, w = tid >> 6, lane = tid & 63;
  Tw t = make_tw<false>(lane);
  int chunk = blockIdx.x & 15, cq = (blockIdx.x >> 4) & 3, tb = blockIdx.x >> 6;
  int i0 = chunk << 4;
  const __half2* wp = (const __half2*)(Wh + (size_t)tb * HWn * Cn);
  float4 nyacc = make_float4(0.f, 0.f, 0.f, 0.f);
  for (int h = 0; h < 2; ++h) {
    if (h) __syncthreads();                  // scratch reuse across halves
    int r0 = i0 + h * 8 + 2 * w;             // wave's row pair
    float2 v[4][4];
#pragma unroll
    for (int q = 0; q < 4; ++q) {
      int j = lane + (q << 6);
      __half2 p00 = wp[(size_t)(((r0    ) << 8) + j) * 8 + cq * 2    ];
      __half2 p01 = wp[(size_t)(((r0    ) << 8) + j) * 8 + cq * 2 + 1];
      __half2 p10 = wp[(size_t)(((r0 + 1) << 8) + j) * 8 + cq * 2    ];
      __half2 p11 = wp[(size_t)(((r0 + 1) << 8) + j) * 8 + cq * 2 + 1];
      float2 f00 = __half22float2(p00), f01 = __half22float2(p01);
      float2 f10 = __half22float2(p10), f11 = __half22float2(p11);
      v[0][q] = make_float2(f00.x, f10.x);
      v[1][q] = make_float2(f00.y, f10.y);
      v[2][q] = make_float2(f01.x, f11.x);
      v[3][q] = make_float2(f01.y, f11.y);
      nyacc.x += f00.x*f00.x + f10.x*f10.x;
      nyacc.y += f00.y*f00.y + f10.y*f10.y;
      nyacc.z += f01.x*f01.x + f11.x*f11.x;
      nyacc.w += f01.y*f01.y + f11.y*f11.y;
    }
    fft256_n<false, 4>(v, sb[w], lane, t);
    __syncthreads();
    // store phase: thread (ii=row 0..7, kq) Hermitian-unpacks from scratch
    int ii = tid & 7, kq = tid >> 3;
    int w2 = ii >> 1, odd = ii & 1;
#pragma unroll
    for (int p = 0; p < 5; ++p) {
      int k = p * 32 + kq;
      if (k <= 128) {
        int kc = (256 - k) & 255;
#pragma unroll
        for (int cc = 0; cc < 4; ++cc) {
          float2 Z  = sb[w2][cc][swz(k)];
          float2 Zc = sb[w2][cc][swz(kc)];
          float2 F = odd ? make_float2(0.5f * (Z.y + Zc.y), 0.5f * (Zc.x - Z.x))
                         : make_float2(0.5f * (Z.x + Zc.x), 0.5f * (Z.y - Zc.y));
          Yh[((size_t)(tb * Cn + cq * 4 + cc) * KF + k) * Hn + i0 + h * 8 + ii] =
              __float22half2_rn(F);
        }
      }
    }
  }
#pragma unroll
  for (int o = 32; o > 0; o >>= 1) {
    nyacc.x += __shfl_down(nyacc.x, o, 64);
    nyacc.y += __shfl_down(nyacc.y, o, 64);
    nyacc.z += __shfl_down(nyacc.z, o, 64);
    nyacc.w += __shfl_down(nyacc.w, o, 64);
  }
  if (lane == 0) redw[w] = nyacc;
  __syncthreads();
  if (tid == 0) {
    float4 s = make_float4(redw[0].x + redw[1].x + redw[2].x + redw[3].x,
                           redw[0].y + redw[1].y + redw[2].y + redw[3].y,
                           redw[0].z + redw[1].z + redw[2].z + redw[3].z,
                           redw[0].w + redw[1].w + redw[2].w + redw[3].w);
    part[((size_t)tb * Cn + cq * 4 + 0) * 16 + chunk] = s.x;
    part[((size_t)tb * Cn + cq * 4 + 1) * 16 + chunk] = s.y;
    part[((size_t)tb * Cn + cq * 4 + 2) * 16 + chunk] = s.z;
    part[((size_t)tb * Cn + cq * 4 + 3) * 16 + chunk] = s.w;
  }
}

// ---------------------------------------------------------------------------
// Column FFT of x spectra, q4-batched: each wave does 4 consecutive items.
// ---------------------------------------------------------------------------
__global__ __launch_bounds__(256) void k_colfft_fx(const __half2* __restrict__ Yh,
                                                   __half2* __restrict__ Fxh) {
  __shared__ float2 sb[4][4][SRL];
  int tid = threadIdx.x, w = tid >> 6, lane = tid & 63;
  Tw t = make_tw<false>(lane);
  int base_item = blockIdx.x * 16 + w * 4;   // (b*16+c)*KF + k
  float2 v[4][4];
#pragma unroll
  for (int f = 0; f < 4; ++f) {
    const __half2* Sp = Yh + (size_t)(base_item + f) * Hn;
#pragma unroll
    for (int q = 0; q < 4; ++q) v[f][q] = __half22float2(Sp[lane + (q << 6)]);
  }
  fft256_n<false, 4>(v, sb[w], lane, t);
#pragma unroll
  for (int f = 0; f < 4; ++f) {
    __half2* Op = Fxh + (size_t)(base_item + f) * Hn;
#pragma unroll
    for (int q = 0; q < 4; ++q) {
      int j = lane + (q << 6);
      Op[j] = __float22half2_rn(sb[w][f][swz(j)]);
    }
  }
}

// ---------------------------------------------------------------------------
// Block = (tb, k-quartet): 4 waves, wave w owns k = quart*4+w. Channels in
// x2-batched pairs. Fused inverse FFT, then one barrier + cooperative 32B-
// granule transposed store into G[tb][j][k].
// ---------------------------------------------------------------------------
__global__ __launch_bounds__(256) void k_ycol(const __half2* __restrict__ Yh,
                                              const __half2* __restrict__ Fxh,
                                              const float* __restrict__ part,
                                              float2* __restrict__ G) {
  __shared__ float2 sb[4][2][SRL];
  __shared__ float scs[16];
  int tid = threadIdx.x, w = tid >> 6, lane = tid & 63;
  int tb = blockIdx.x / 33, quart = blockIdx.x % 33;
  int b = tb & 3;
  if (tid < 16) {
    float sx = 0.f, sy = 0.f;
#pragma unroll
    for (int ch = 0; ch < 16; ++ch) {
      sx += part[((size_t)b  * Cn + tid) * 16 + ch];   // t=0 slab == x norms
      sy += part[((size_t)tb * Cn + tid) * 16 + ch];
    }
    scs[tid] = 1.0f / ((float)Cn * (sqrtf(sx) * sqrtf(sy) + 1e-12f));
  }
  __syncthreads();
  int k = quart * 4 + w;
  bool act = (k <= 128);
  if (act) {
    Tw tf = make_tw<false>(lane);
    float2 acc[4];
#pragma unroll
    for (int q = 0; q < 4; ++q) acc[q] = make_float2(0.f, 0.f);
    for (int c = 0; c < Cn; c += 2) {
      float2 v2[2][4];
#pragma unroll
      for (int e = 0; e < 2; ++e) {
        const __half2* Yp = Yh + ((size_t)(tb * Cn + c + e) * KF + k) * Hn;
#pragma unroll
        for (int q = 0; q < 4; ++q) v2[e][q] = __half22float2(Yp[lane + (q << 6)]);
      }
      fft256_n<false, 2>(v2, sb[w], lane, tf);
#pragma unroll
      for (int e = 0; e < 2; ++e) {
        float sc = scs[c + e];
        const __half2* Fxp = Fxh + ((size_t)(b * Cn + c + e) * KF + k) * Hn;
#pragma unroll
        for (int q = 0; q < 4; ++q) {
          int rr = lane + (q << 6);
          float2 fy = sb[w][e][swz(rr)];
          float2 fx = __half22float2(Fxp[rr]);
          acc[q].x += sc * (fx.x * fy.x + fx.y * fy.y);   // fx * conj(fy)
          acc[q].y += sc * (fx.y * fy.x - fx.x * fy.y);
        }
      }
    }
    Tw ti = make_tw<true>(lane);
    fft256_n<true, 1>(reinterpret_cast<float2(*)[4]>(acc), sb[w], lane, ti);
  }
  __syncthreads();
  // transposed store: 4 consecutive k per j -> 32B granules
  int kk = tid & 3, jj0 = tid >> 2;
  if (quart * 4 + kk <= 128) {
    float2* Gp = G + ((size_t)tb * Hn) * KGP + quart * 4 + kk;
#pragma unroll
    for (int p = 0; p < 4; ++p) {
      int j = jj0 + (p << 6);
      Gp[(size_t)j * KGP] = sb[kk][0][swz(j)];
    }
  }
}

// ---------------------------------------------------------------------------
// Final pass: block = (b, spatial row i), 5 waves. Wave tp handles t-pair
// (2tp, 2tp+1): Hermitian-extend both spectra, pack A + iB, ONE inverse FFT,
// re/im are the two t's correlations. G reads fully contiguous.
// ---------------------------------------------------------------------------
__global__ __launch_bounds__(320) void k_irow(const float2* __restrict__ G,
                                              float* __restrict__ out) {
  __shared__ float2 tile[5][2][132];
  __shared__ float2 sb[5][SRL];
  __shared__ float rowbuf[Wn * NTn];
  int tid = threadIdx.x, w = tid >> 6, lane = tid & 63;
  Tw ti = make_tw<true>(lane);
  int b = blockIdx.x >> 8, i = blockIdx.x & 255;
  const float scale = 1.0f / ((float)Hn * (float)Wn);
  int t1 = 2 * w, t2 = t1 + 1;
  {
    const float2* Gp1 = G + ((size_t)(t1 * Bn + b) * Hn + i) * KGP;
    for (int k = lane; k < KF; k += 64) tile[w][0][k] = Gp1[k];
    if (t2 < NTn) {
      const float2* Gp2 = G + ((size_t)(t2 * Bn + b) * Hn + i) * KGP;
      for (int k = lane; k < KF; k += 64) tile[w][1][k] = Gp2[k];
    }
  }
  lds_fence();   // tile[w] is wave-private
  float2 v[1][4];
#pragma unroll
  for (int q = 0; q < 4; ++q) {
    int k = lane + (q << 6);
    float2 a, bb;
    if (k <= 128) a = tile[w][0][k];
    else { float2 z = tile[w][0][256 - k]; a = make_float2(z.x, -z.y); }
    if (t2 < NTn) {
      if (k <= 128) bb = tile[w][1][k];
      else { float2 z = tile[w][1][256 - k]; bb = make_float2(z.x, -z.y); }
    } else bb = make_float2(0.f, 0.f);
    v[0][q] = make_float2(a.x - bb.y, a.y + bb.x);   // A + i*B
  }
  fft256_n<true, 1>(v, reinterpret_cast<float2(*)[SRL]>(sb[w]), lane, ti);
#pragma unroll
  for (int q = 0; q < 4; ++q) {
    int j = lane + (q << 6);
    float2 r = sb[w][swz(j)];
    rowbuf[j * NTn + t1] = r.x * scale;
    if (t2 < NTn) rowbuf[j * NTn + t2] = r.y * scale;
  }
  __syncthreads();
  float* ob = out + ((size_t)(b * Hn + i) * Wn) * NTn;
  for (int f = tid; f < Wn * NTn; f += 320) ob[f] = rowbuf[f];
}

// ---------------------------------------------------------------------------
extern "C" void kernel_launch(void* const* d_in, const int* in_sizes, int n_in,
                              void* d_out, int out_size, void* d_ws, size_t ws_size,
                              hipStream_t stream) {
  const float* inp = (const float*)d_in[0];
  const float* T   = (const float*)d_in[1];
  float* out = (float*)d_out;
  char* ws = (char*)d_ws;

  size_t off = 0;
  float*   part = (float*)(ws + off);  off += (size_t)NTn * Bn * Cn * 16 * sizeof(float);   // 36 KB
  __half2* Fxh = (__half2*)(ws + off); off += (size_t)Bn * Cn * KF * Hn * sizeof(__half2);  // 8.5 MB
  float2*  G   = (float2*)(ws + off);  off += (size_t)NTn * Bn * Hn * KGP * sizeof(float2); // 10.0 MB
  __half*  Wh  = (__half*)(ws + off);  off += (size_t)NTn * Bn * HWn * Cn * sizeof(__half); // 75.5 MB
  __half2* Yh  = (__half2*)(ws + off); off += (size_t)NTn * Bn * Cn * KF * Hn * sizeof(__half2); // 76 MB
  (void)off; (void)ws_size; (void)in_sizes; (void)n_in; (void)out_size;

  k_gather<<<NTn * Bn * 256, 256, 0, stream>>>(inp, T, Wh);
  k_yfft<<<NTn * Bn * 64, 256, 0, stream>>>(Wh, Yh, part);
  k_colfft_fx<<<Bn * Cn * KF / 16, 256, 0, stream>>>(Yh, Fxh);   // 516 blocks
  k_ycol<<<NTn * Bn * 33, 256, 0, stream>>>(Yh, Fxh, part, G);
  k_irow<<<Bn * Hn, 320, 0, stream>>>(G, out);
}